// Round 1
// baseline (631.321 us; speedup 1.0000x reference)
//
#include <hip/hip_runtime.h>
#include <cmath>

#define NUM_HEADS 8
#define MAX_POINTS 8
#define HD 64

// ---------------------------------------------------------------------------
// GEMM: C[M,N] = A[M,K] @ B[K,N] + bias[N]   (fp32, 64x64x16 tiles, 4x4/thread)
// ---------------------------------------------------------------------------
#define BM 64
#define BN 64
#define BK 16

__global__ __launch_bounds__(256) void gemm_bias_f32(
    const float* __restrict__ A, const float* __restrict__ Bm,
    const float* __restrict__ bias, float* __restrict__ C,
    int M, int N, int K)
{
    __shared__ float As[BK][BM];   // As[k][m]
    __shared__ float Bs[BK][BN];   // Bs[k][n]
    int tid = threadIdx.x;
    int tx = tid & 15, ty = tid >> 4;
    int bm = blockIdx.y * BM;
    int bn = blockIdx.x * BN;

    float acc[4][4] = {};
    int arow = tid >> 2;            // 0..63 (m within tile)
    int acol = (tid & 3) << 2;      // 0,4,8,12 (k within tile)
    int brow = tid >> 4;            // 0..15 (k within tile)
    int bcol = (tid & 15) << 2;     // 0..60 (n within tile)

    for (int k0 = 0; k0 < K; k0 += BK) {
        float4 av = *(const float4*)&A[(size_t)(bm + arow) * K + k0 + acol];
        As[acol + 0][arow] = av.x;
        As[acol + 1][arow] = av.y;
        As[acol + 2][arow] = av.z;
        As[acol + 3][arow] = av.w;
        *(float4*)&Bs[brow][bcol] =
            *(const float4*)&Bm[(size_t)(k0 + brow) * N + bn + bcol];
        __syncthreads();
#pragma unroll
        for (int kk = 0; kk < BK; ++kk) {
            float4 a = *(const float4*)&As[kk][ty * 4];
            float4 b = *(const float4*)&Bs[kk][tx * 4];
            float aa[4] = {a.x, a.y, a.z, a.w};
            float bb[4] = {b.x, b.y, b.z, b.w};
#pragma unroll
            for (int i = 0; i < 4; ++i)
#pragma unroll
                for (int j = 0; j < 4; ++j)
                    acc[i][j] = fmaf(aa[i], bb[j], acc[i][j]);
        }
        __syncthreads();
    }
    float4 bv = *(const float4*)&bias[bn + tx * 4];
    float bb[4] = {bv.x, bv.y, bv.z, bv.w};
#pragma unroll
    for (int i = 0; i < 4; ++i) {
        float4 o;
        o.x = acc[i][0] + bb[0];
        o.y = acc[i][1] + bb[1];
        o.z = acc[i][2] + bb[2];
        o.w = acc[i][3] + bb[3];
        *(float4*)&C[(size_t)(bm + ty * 4 + i) * N + bn + tx * 4] = o;
    }
}

// ---------------------------------------------------------------------------
// Transpose ref (B,C,S) -> refT (B,S,C), S = H*W.  32x32 LDS tiles.
// ---------------------------------------------------------------------------
__global__ __launch_bounds__(256) void transpose_ref_k(
    const float* __restrict__ in, float* __restrict__ out, int C, int S)
{
    __shared__ float tile[32][33];
    int b = blockIdx.z;
    int c0 = blockIdx.x * 32;
    int s0 = blockIdx.y * 32;
    int tx = threadIdx.x, ty = threadIdx.y;
    const float* ib = in + (size_t)b * C * S;
    float* ob = out + (size_t)b * S * C;
#pragma unroll
    for (int i = 0; i < 32; i += 8)
        tile[ty + i][tx] = ib[(size_t)(c0 + ty + i) * S + s0 + tx];
    __syncthreads();
#pragma unroll
    for (int i = 0; i < 32; i += 8)
        ob[(size_t)(s0 + ty + i) * C + c0 + tx] = tile[tx][ty + i];
}

// ---------------------------------------------------------------------------
// Fused bilinear sample + softmax attention.
// One wave per (b,n,h); lane = channel d (hd == 64 == wavefront).
// refT layout: (B, H, W, C) so each tap reads 64 contiguous floats.
// ---------------------------------------------------------------------------
__global__ __launch_bounds__(256) void sample_attn_k(
    const float* __restrict__ qb, const float* __restrict__ offb,
    const float* __restrict__ refT, float* __restrict__ ob,
    const int* __restrict__ Hp, const int* __restrict__ Wp,
    const int* __restrict__ npp, int B, int N, int C)
{
    int H = *Hp, W = *Wp, npts = *npp;
    int wave = blockIdx.x * 4 + (threadIdx.x >> 6);
    int lane = threadIdx.x & 63;
    int h = wave & (NUM_HEADS - 1);
    int bn = wave >> 3;          // b*N + n
    int n = bn % N;
    int b = bn / N;

    int row = n / W, col = n % W;
    float q_val = qb[(size_t)bn * C + h * HD + lane];
    const float* op = offb + (size_t)bn * (NUM_HEADS * MAX_POINTS * 2)
                    + h * (MAX_POINTS * 2);
    const float* rb = refT + (size_t)b * ((size_t)H * W) * C + h * HD + lane;

    // x_pix = loc0*(W-1)/(H-1), y_pix = loc1*(H-1)/(W-1)  (ref's g0/g1 swap)
    float rX = (H > 1) ? (float)(W - 1) / (float)(H - 1) : 0.f;
    float rY = (W > 1) ? (float)(H - 1) / (float)(W - 1) : 0.f;

    float sv[MAX_POINTS];
    float lg[MAX_POINTS];
#pragma unroll
    for (int p = 0; p < MAX_POINTS; ++p) {
        bool act = p < npts;
        float off0 = op[p * 2 + 0];
        float off1 = op[p * 2 + 1];
        float x = ((float)row + off0) * rX;
        float y = ((float)col + off1) * rY;
        float x0f = floorf(x), y0f = floorf(y);
        int x0 = (int)x0f, y0 = (int)y0f;
        int x1 = x0 + 1, y1 = y0 + 1;
        float wx1 = x - x0f, wx0 = 1.f - wx1;
        float wy1 = y - y0f, wy0 = 1.f - wy1;
        float v = 0.f;
        if (y0 >= 0 && y0 < H && x0 >= 0 && x0 < W)
            v = fmaf(rb[((size_t)y0 * W + x0) * C], wy0 * wx0, v);
        if (y0 >= 0 && y0 < H && x1 >= 0 && x1 < W)
            v = fmaf(rb[((size_t)y0 * W + x1) * C], wy0 * wx1, v);
        if (y1 >= 0 && y1 < H && x0 >= 0 && x0 < W)
            v = fmaf(rb[((size_t)y1 * W + x0) * C], wy1 * wx0, v);
        if (y1 >= 0 && y1 < H && x1 >= 0 && x1 < W)
            v = fmaf(rb[((size_t)y1 * W + x1) * C], wy1 * wx1, v);
        sv[p] = v;
        float t = q_val * v;
#pragma unroll
        for (int o = 32; o > 0; o >>= 1) t += __shfl_xor(t, o);
        lg[p] = act ? t : -1e30f;
    }

    float scale = 1.0f / sqrtf((float)HD);
    float mx = -1e30f;
#pragma unroll
    for (int p = 0; p < MAX_POINTS; ++p) {
        lg[p] *= scale;
        mx = fmaxf(mx, lg[p]);
    }
    float ssum = 0.f;
#pragma unroll
    for (int p = 0; p < MAX_POINTS; ++p) {
        lg[p] = expf(lg[p] - mx);
        ssum += lg[p];
    }
    float inv = 1.f / ssum;
    float outv = 0.f;
#pragma unroll
    for (int p = 0; p < MAX_POINTS; ++p) outv += lg[p] * sv[p];
    outv *= inv;
    ob[(size_t)bn * C + h * HD + lane] = outv;
}

// ---------------------------------------------------------------------------
// Launch
// ---------------------------------------------------------------------------
extern "C" void kernel_launch(void* const* d_in, const int* in_sizes, int n_in,
                              void* d_out, int out_size, void* d_ws, size_t ws_size,
                              hipStream_t stream) {
    const float* query = (const float*)d_in[0];
    const float* ref   = (const float*)d_in[1];
    const float* q_w   = (const float*)d_in[2];
    const float* q_b   = (const float*)d_in[3];
    // d_in[4], d_in[5]: kv_w, kv_b -- unused by the reference forward
    const float* off_w = (const float*)d_in[6];
    const float* off_b = (const float*)d_in[7];
    const float* out_w = (const float*)d_in[8];
    const float* out_b = (const float*)d_in[9];
    const int* Hp   = (const int*)d_in[10];
    const int* Wp   = (const int*)d_in[11];
    const int* npp  = (const int*)d_in[12];

    const int C = 512;           // from q_w (512*512); hd = C/8 = 64
    const int B = 4;
    const int H = 64, W = 64;
    const int N = H * W;         // 4096
    const int M = B * N;         // 16384
    const int OFFD = NUM_HEADS * MAX_POINTS * 2;  // 128

    float* qbuf   = (float*)d_ws;                  // M*C
    float* obuf   = qbuf   + (size_t)M * C;        // M*C
    float* offbuf = obuf   + (size_t)M * C;        // M*OFFD
    float* refT   = offbuf + (size_t)M * OFFD;     // M*C

    dim3 blk(256);
    gemm_bias_f32<<<dim3(C / BN, M / BM), blk, 0, stream>>>(
        query, q_w, q_b, qbuf, M, C, C);
    gemm_bias_f32<<<dim3(OFFD / BN, M / BM), blk, 0, stream>>>(
        query, off_w, off_b, offbuf, M, OFFD, C);
    transpose_ref_k<<<dim3(C / 32, N / 32, B), dim3(32, 8), 0, stream>>>(
        ref, refT, C, N);
    sample_attn_k<<<dim3(M * NUM_HEADS / 4), blk, 0, stream>>>(
        qbuf, offbuf, refT, obuf, Hp, Wp, npp, B, N, C);
    gemm_bias_f32<<<dim3(C / BN, M / BM), blk, 0, stream>>>(
        obuf, out_w, out_b, (float*)d_out, M, C, C);
}

// Round 3
// 248.769 us; speedup vs baseline: 2.5378x; 2.5378x over previous
//
#include <hip/hip_runtime.h>
#include <cmath>

#define NUM_HEADS 8
#define MAX_POINTS 8
#define HD 64

typedef short bf16x8 __attribute__((ext_vector_type(8)));
typedef float f32x4 __attribute__((ext_vector_type(4)));

__device__ __forceinline__ unsigned short f2bf(float f) {
    unsigned u = __float_as_uint(f);
    unsigned r = (u + 0x7fff + ((u >> 16) & 1)) >> 16;   // RNE
    return (unsigned short)r;
}
__device__ __forceinline__ float bf2f(unsigned short s) {
    return __uint_as_float(((unsigned)s) << 16);
}

// ---------------------------------------------------------------------------
// fp32 -> bf16 elementwise convert (n divisible by 4)
// ---------------------------------------------------------------------------
__global__ __launch_bounds__(256) void cvt_bf16_k(
    const float* __restrict__ in, unsigned short* __restrict__ out, int n)
{
    int i = (blockIdx.x * 256 + threadIdx.x) * 4;
    if (i >= n) return;
    float4 v = *(const float4*)&in[i];
    ushort4 o;
    o.x = f2bf(v.x); o.y = f2bf(v.y); o.z = f2bf(v.z); o.w = f2bf(v.w);
    *(ushort4*)&out[i] = o;
}

// ---------------------------------------------------------------------------
// Weight transpose + convert: in (K,N) fp32 -> out (N,K) bf16. 32x32 tiles.
// ---------------------------------------------------------------------------
__global__ __launch_bounds__(256) void tconv_w_k(
    const float* __restrict__ in, unsigned short* __restrict__ out, int K, int N)
{
    __shared__ float tile[32][33];
    int k0 = blockIdx.x * 32, n0 = blockIdx.y * 32;
    int tx = threadIdx.x, ty = threadIdx.y;
#pragma unroll
    for (int i = 0; i < 32; i += 8)
        tile[ty + i][tx] = in[(size_t)(k0 + ty + i) * N + n0 + tx];
    __syncthreads();
#pragma unroll
    for (int i = 0; i < 32; i += 8)
        out[(size_t)(n0 + ty + i) * K + k0 + tx] = f2bf(tile[tx][ty + i]);
}

// ---------------------------------------------------------------------------
// Transpose ref (B,C,S) -> refT (B,S,C) fp32, S = H*W.
// ---------------------------------------------------------------------------
__global__ __launch_bounds__(256) void transpose_ref_k(
    const float* __restrict__ in, float* __restrict__ out, int C, int S)
{
    __shared__ float tile[32][33];
    int b = blockIdx.z;
    int c0 = blockIdx.x * 32;
    int s0 = blockIdx.y * 32;
    int tx = threadIdx.x, ty = threadIdx.y;
    const float* ib = in + (size_t)b * C * S;
    float* ob = out + (size_t)b * S * C;
#pragma unroll
    for (int i = 0; i < 32; i += 8)
        tile[ty + i][tx] = ib[(size_t)(c0 + ty + i) * S + s0 + tx];
    __syncthreads();
#pragma unroll
    for (int i = 0; i < 32; i += 8)
        ob[(size_t)(s0 + ty + i) * C + c0 + tx] = tile[tx][ty + i];
}

// ---------------------------------------------------------------------------
// bf16 MFMA GEMM: C[M,N] = A[M,K] @ BT[N,K]^T + bias.
// 64x64 tile, BK=32, 4 waves/block each computing a 32x32 quadrant via
// 4x mfma_f32_16x16x32_bf16. Writes fp32 (Cf) or bf16 (Cb).
// LDS rows padded to 40 shorts (80 B) -> 2-way bank aliasing (free).
// ---------------------------------------------------------------------------
#define LDK 40

__global__ __launch_bounds__(256) void gemm_bf16_mfma(
    const unsigned short* __restrict__ A, const unsigned short* __restrict__ BT,
    const float* __restrict__ bias, float* __restrict__ Cf,
    unsigned short* __restrict__ Cb, int M, int N, int K)
{
    __shared__ unsigned short As[64 * LDK];
    __shared__ unsigned short Bs[64 * LDK];
    int tid = threadIdx.x;
    int wave = tid >> 6, lane = tid & 63;
    int quad = lane >> 4, l16 = lane & 15;
    int bm = blockIdx.y * 64, bn = blockIdx.x * 64;
    int wm = (wave >> 1) * 32, wn = (wave & 1) * 32;

    int srow = tid >> 2, schunk = (tid & 3) * 8;   // staging: row 0..63, 8 shorts

    f32x4 acc[2][2];
#pragma unroll
    for (int i = 0; i < 2; ++i)
#pragma unroll
        for (int j = 0; j < 2; ++j)
            acc[i][j] = (f32x4){0.f, 0.f, 0.f, 0.f};

    for (int k0 = 0; k0 < K; k0 += 32) {
        *(uint4*)&As[srow * LDK + schunk] =
            *(const uint4*)&A[(size_t)(bm + srow) * K + k0 + schunk];
        *(uint4*)&Bs[srow * LDK + schunk] =
            *(const uint4*)&BT[(size_t)(bn + srow) * K + k0 + schunk];
        __syncthreads();
        bf16x8 af[2], bfr[2];
#pragma unroll
        for (int t = 0; t < 2; ++t) {
            af[t]  = *(const bf16x8*)&As[(wm + t * 16 + l16) * LDK + quad * 8];
            bfr[t] = *(const bf16x8*)&Bs[(wn + t * 16 + l16) * LDK + quad * 8];
        }
#pragma unroll
        for (int mt = 0; mt < 2; ++mt)
#pragma unroll
            for (int nt = 0; nt < 2; ++nt)
                acc[mt][nt] = __builtin_amdgcn_mfma_f32_16x16x32_bf16(
                    af[mt], bfr[nt], acc[mt][nt], 0, 0, 0);
        __syncthreads();
    }

    // C/D layout: col = lane&15, row = (lane>>4)*4 + reg   [m89/m91]
#pragma unroll
    for (int mt = 0; mt < 2; ++mt)
#pragma unroll
        for (int nt = 0; nt < 2; ++nt) {
            int r0 = bm + wm + mt * 16 + quad * 4;
            int c  = bn + wn + nt * 16 + l16;
            float bv = bias[c];
#pragma unroll
            for (int r = 0; r < 4; ++r) {
                float v = acc[mt][nt][r] + bv;
                if (Cf) Cf[(size_t)(r0 + r) * N + c] = v;
                if (Cb) Cb[(size_t)(r0 + r) * N + c] = f2bf(v);
            }
        }
}

// ---------------------------------------------------------------------------
// Fused bilinear sample + softmax attention, float4 channels.
// One wave = 4 heads x 16 lanes; lane handles 4 channels of one head.
// ---------------------------------------------------------------------------
__global__ __launch_bounds__(256) void sample_attn4_k(
    const unsigned short* __restrict__ qb, const float* __restrict__ offb,
    const float* __restrict__ refT, unsigned short* __restrict__ ob,
    const int* __restrict__ Hp, const int* __restrict__ Wp,
    const int* __restrict__ npp, int B, int N, int C)
{
    int H = *Hp, W = *Wp, npts = *npp;
    int wid = blockIdx.x * 4 + (threadIdx.x >> 6);
    int lane = threadIdx.x & 63;
    int hg = wid & 1;
    int bn = wid >> 1;
    int b = bn / N, n = bn % N;
    int h = hg * 4 + (lane >> 4);
    int c4 = (lane & 15) * 4;
    int coff = h * HD + c4;
    int row = n / W, col = n % W;

    ushort4 qs = *(const ushort4*)&qb[(size_t)bn * C + coff];
    float q0 = bf2f(qs.x), q1 = bf2f(qs.y), q2 = bf2f(qs.z), q3 = bf2f(qs.w);

    const float* op = offb + (size_t)bn * (NUM_HEADS * MAX_POINTS * 2)
                    + h * (MAX_POINTS * 2);
    const float* rb = refT + (size_t)b * ((size_t)H * W) * C;

    float rX = (H > 1) ? (float)(W - 1) / (float)(H - 1) : 0.f;
    float rY = (W > 1) ? (float)(H - 1) / (float)(W - 1) : 0.f;

    f32x4 sv[MAX_POINTS];
    float lg[MAX_POINTS];
#pragma unroll
    for (int p = 0; p < MAX_POINTS; ++p) {
        float off0 = op[p * 2 + 0];
        float off1 = op[p * 2 + 1];
        float x = ((float)row + off0) * rX;
        float y = ((float)col + off1) * rY;
        float x0f = floorf(x), y0f = floorf(y);
        int x0 = (int)x0f, y0 = (int)y0f;
        float wx1 = x - x0f, wx0 = 1.f - wx1;
        float wy1 = y - y0f, wy0 = 1.f - wy1;

        f32x4 v = (f32x4){0.f, 0.f, 0.f, 0.f};
#pragma unroll
        for (int t = 0; t < 4; ++t) {
            int yi = y0 + (t >> 1);
            int xi = x0 + (t & 1);
            float wgt = ((t >> 1) ? wy1 : wy0) * ((t & 1) ? wx1 : wx0);
            bool ok = (yi >= 0) & (yi < H) & (xi >= 0) & (xi < W);
            float wv = ok ? wgt : 0.f;
            int yc = min(max(yi, 0), H - 1);
            int xc = min(max(xi, 0), W - 1);
            const f32x4 src = *(const f32x4*)&rb[((size_t)yc * W + xc) * C + coff];
            v += wv * src;
        }
        sv[p] = v;
        float t = q0 * v[0] + q1 * v[1] + q2 * v[2] + q3 * v[3];
        t += __shfl_xor(t, 1);
        t += __shfl_xor(t, 2);
        t += __shfl_xor(t, 4);
        t += __shfl_xor(t, 8);
        lg[p] = (p < npts) ? t * 0.125f : -1e30f;   // scale = hd^-0.5
    }

    float mx = -1e30f;
#pragma unroll
    for (int p = 0; p < MAX_POINTS; ++p) mx = fmaxf(mx, lg[p]);
    float ssum = 0.f;
#pragma unroll
    for (int p = 0; p < MAX_POINTS; ++p) {
        lg[p] = __expf(lg[p] - mx);
        ssum += lg[p];
    }
    float inv = 1.f / ssum;
    f32x4 outv = (f32x4){0.f, 0.f, 0.f, 0.f};
#pragma unroll
    for (int p = 0; p < MAX_POINTS; ++p) outv += lg[p] * sv[p];

    ushort4 o;
    o.x = f2bf(outv[0] * inv); o.y = f2bf(outv[1] * inv);
    o.z = f2bf(outv[2] * inv); o.w = f2bf(outv[3] * inv);
    *(ushort4*)&ob[(size_t)bn * C + coff] = o;
}

// ---------------------------------------------------------------------------
// Launch
// ---------------------------------------------------------------------------
extern "C" void kernel_launch(void* const* d_in, const int* in_sizes, int n_in,
                              void* d_out, int out_size, void* d_ws, size_t ws_size,
                              hipStream_t stream) {
    const float* query = (const float*)d_in[0];
    const float* ref   = (const float*)d_in[1];
    const float* q_w   = (const float*)d_in[2];
    const float* q_b   = (const float*)d_in[3];
    // d_in[4], d_in[5]: kv_w, kv_b -- unused by the reference forward
    const float* off_w = (const float*)d_in[6];
    const float* off_b = (const float*)d_in[7];
    const float* out_w = (const float*)d_in[8];
    const float* out_b = (const float*)d_in[9];
    const int* Hp   = (const int*)d_in[10];
    const int* Wp   = (const int*)d_in[11];
    const int* npp  = (const int*)d_in[12];

    const int C = 512;
    const int B = 4;
    const int H = 64, W = 64;
    const int N = H * W;              // 4096
    const int M = B * N;              // 16384
    const int OFFD = NUM_HEADS * MAX_POINTS * 2;  // 128

    float* refT   = (float*)d_ws;                                   // M*C f32
    float* offbuf = refT + (size_t)M * C;                           // M*OFFD f32
    unsigned short* qin_bf  = (unsigned short*)(offbuf + (size_t)M * OFFD); // M*C
    unsigned short* qbuf_bf = qin_bf  + (size_t)M * C;              // M*C
    unsigned short* obuf_bf = qbuf_bf + (size_t)M * C;              // M*C
    unsigned short* wqT     = obuf_bf + (size_t)M * C;              // C*C
    unsigned short* woffT   = wqT   + (size_t)C * C;                // OFFD*C
    unsigned short* woutT   = woffT + (size_t)OFFD * C;             // C*C

    dim3 blk(256);
    // prep: converts + transposes
    cvt_bf16_k<<<dim3((M * C) / 1024), blk, 0, stream>>>(query, qin_bf, M * C);
    tconv_w_k<<<dim3(C / 32, C / 32), dim3(32, 8), 0, stream>>>(q_w, wqT, C, C);
    tconv_w_k<<<dim3(C / 32, OFFD / 32), dim3(32, 8), 0, stream>>>(off_w, woffT, C, OFFD);
    tconv_w_k<<<dim3(C / 32, C / 32), dim3(32, 8), 0, stream>>>(out_w, woutT, C, C);
    transpose_ref_k<<<dim3(C / 32, N / 32, B), dim3(32, 8), 0, stream>>>(ref, refT, C, N);

    // q projection (bf16 out) and offset projection (fp32 out)
    gemm_bf16_mfma<<<dim3(C / 64, M / 64), blk, 0, stream>>>(
        qin_bf, wqT, q_b, nullptr, qbuf_bf, M, C, C);
    gemm_bf16_mfma<<<dim3(OFFD / 64, M / 64), blk, 0, stream>>>(
        qin_bf, woffT, off_b, offbuf, nullptr, M, OFFD, C);

    // fused sample + attention -> bf16 obuf
    sample_attn4_k<<<dim3((M * 2) / 4), blk, 0, stream>>>(
        qbuf_bf, offbuf, refT, obuf_bf, Hp, Wp, npp, B, N, C);

    // output projection (fp32 out)
    gemm_bf16_mfma<<<dim3(C / 64, M / 64), blk, 0, stream>>>(
        obuf_bf, woutT, out_b, (float*)d_out, nullptr, M, C, C);
}

// Round 4
// 224.692 us; speedup vs baseline: 2.8097x; 1.1072x over previous
//
#include <hip/hip_runtime.h>
#include <cmath>

#define NUM_HEADS 8
#define MAX_POINTS 8
#define HD 64

typedef short bf16x8 __attribute__((ext_vector_type(8)));
typedef float f32x4 __attribute__((ext_vector_type(4)));

typedef const __attribute__((address_space(1))) unsigned int gu32;
typedef __attribute__((address_space(3))) unsigned int lu32;

__device__ __forceinline__ unsigned short f2bf(float f) {
    unsigned u = __float_as_uint(f);
    unsigned r = (u + 0x7fff + ((u >> 16) & 1)) >> 16;   // RNE
    return (unsigned short)r;
}
__device__ __forceinline__ float bf2f(unsigned short s) {
    return __uint_as_float(((unsigned)s) << 16);
}
__device__ __forceinline__ unsigned packbf2(float a, float b) {
    return (unsigned)f2bf(a) | ((unsigned)f2bf(b) << 16);
}
// unpack uint4 (8 bf16) -> 8 floats
__device__ __forceinline__ void unpack8(uint4 u, float* f) {
    f[0] = __uint_as_float(u.x << 16); f[1] = __uint_as_float(u.x & 0xffff0000u);
    f[2] = __uint_as_float(u.y << 16); f[3] = __uint_as_float(u.y & 0xffff0000u);
    f[4] = __uint_as_float(u.z << 16); f[5] = __uint_as_float(u.z & 0xffff0000u);
    f[6] = __uint_as_float(u.w << 16); f[7] = __uint_as_float(u.w & 0xffff0000u);
}

// ---------------------------------------------------------------------------
// fp32 -> bf16 elementwise convert (n divisible by 4)
// ---------------------------------------------------------------------------
__global__ __launch_bounds__(256) void cvt_bf16_k(
    const float* __restrict__ in, unsigned short* __restrict__ out, int n)
{
    int i = (blockIdx.x * 256 + threadIdx.x) * 4;
    if (i >= n) return;
    float4 v = *(const float4*)&in[i];
    ushort4 o;
    o.x = f2bf(v.x); o.y = f2bf(v.y); o.z = f2bf(v.z); o.w = f2bf(v.w);
    *(ushort4*)&out[i] = o;
}

// ---------------------------------------------------------------------------
// Transpose + convert: in (K,N) fp32 -> out (N,K) bf16. 32x32 tiles.
// Used for weights (K=C) and, batched via blockIdx.z, for ref (C,S)->(S,C).
// ---------------------------------------------------------------------------
__global__ __launch_bounds__(256) void tconv_k(
    const float* __restrict__ in, unsigned short* __restrict__ out, int K, int N)
{
    __shared__ float tile[32][33];
    size_t ib = (size_t)blockIdx.z * K * N;
    int k0 = blockIdx.x * 32, n0 = blockIdx.y * 32;
    int tx = threadIdx.x, ty = threadIdx.y;
#pragma unroll
    for (int i = 0; i < 32; i += 8)
        tile[ty + i][tx] = in[ib + (size_t)(k0 + ty + i) * N + n0 + tx];
    __syncthreads();
#pragma unroll
    for (int i = 0; i < 32; i += 8)
        out[ib + (size_t)(n0 + ty + i) * K + k0 + tx] = f2bf(tile[tx][ty + i]);
}

// ---------------------------------------------------------------------------
// bf16 MFMA GEMM, 64x64 tile (kept for the N=128 offset projection).
// ---------------------------------------------------------------------------
#define LDK 40

__global__ __launch_bounds__(256) void gemm_bf16_mfma64(
    const unsigned short* __restrict__ A, const unsigned short* __restrict__ BT,
    const float* __restrict__ bias, float* __restrict__ Cf,
    unsigned short* __restrict__ Cb, int M, int N, int K)
{
    __shared__ unsigned short As[64 * LDK];
    __shared__ unsigned short Bs[64 * LDK];
    int tid = threadIdx.x;
    int wave = tid >> 6, lane = tid & 63;
    int quad = lane >> 4, l16 = lane & 15;
    int bm = blockIdx.y * 64, bn = blockIdx.x * 64;
    int wm = (wave >> 1) * 32, wn = (wave & 1) * 32;
    int srow = tid >> 2, schunk = (tid & 3) * 8;

    f32x4 acc[2][2];
#pragma unroll
    for (int i = 0; i < 2; ++i)
#pragma unroll
        for (int j = 0; j < 2; ++j)
            acc[i][j] = (f32x4){0.f, 0.f, 0.f, 0.f};

    for (int k0 = 0; k0 < K; k0 += 32) {
        *(uint4*)&As[srow * LDK + schunk] =
            *(const uint4*)&A[(size_t)(bm + srow) * K + k0 + schunk];
        *(uint4*)&Bs[srow * LDK + schunk] =
            *(const uint4*)&BT[(size_t)(bn + srow) * K + k0 + schunk];
        __syncthreads();
        bf16x8 af[2], bfr[2];
#pragma unroll
        for (int t = 0; t < 2; ++t) {
            af[t]  = *(const bf16x8*)&As[(wm + t * 16 + l16) * LDK + quad * 8];
            bfr[t] = *(const bf16x8*)&Bs[(wn + t * 16 + l16) * LDK + quad * 8];
        }
#pragma unroll
        for (int mt = 0; mt < 2; ++mt)
#pragma unroll
            for (int nt = 0; nt < 2; ++nt)
                acc[mt][nt] = __builtin_amdgcn_mfma_f32_16x16x32_bf16(
                    af[mt], bfr[nt], acc[mt][nt], 0, 0, 0);
        __syncthreads();
    }
#pragma unroll
    for (int mt = 0; mt < 2; ++mt)
#pragma unroll
        for (int nt = 0; nt < 2; ++nt) {
            int r0 = bm + wm + mt * 16 + quad * 4;
            int c  = bn + wn + nt * 16 + l16;
            float bv = bias[c];
#pragma unroll
            for (int r = 0; r < 4; ++r) {
                float v = acc[mt][nt][r] + bv;
                if (Cf) Cf[(size_t)(r0 + r) * N + c] = v;
                if (Cb) Cb[(size_t)(r0 + r) * N + c] = f2bf(v);
            }
        }
}

// ---------------------------------------------------------------------------
// bf16 MFMA GEMM, 128x128 tile, global_load_lds(16B) staging (m97 structure).
// 4 waves, each 64x64 quadrant = 4x4 frags of 16x16x32. BK=32, LDS 16 KB.
// LDS layout row-major contiguous (no pad) -- forced by global_load_lds
// wave-uniform-base + lane*16 semantics; bank distribution is balanced.
// ---------------------------------------------------------------------------
__global__ __launch_bounds__(256) void gemm_bf16_mfma128(
    const unsigned short* __restrict__ A, const unsigned short* __restrict__ BT,
    const float* __restrict__ bias, float* __restrict__ Cf,
    unsigned short* __restrict__ Cb, int M, int N, int K)
{
    __shared__ unsigned short As[128 * 32];
    __shared__ unsigned short Bs[128 * 32];
    int tid = threadIdx.x;
    int wave = tid >> 6, lane = tid & 63;
    int quad = lane >> 4, l16 = lane & 15;
    int bm = blockIdx.y * 128, bn = blockIdx.x * 128;
    int wm = (wave >> 1) * 64, wn = (wave & 1) * 64;

    // staging: chunk c = row*4 + q  (row = c>>2, 16B chunk q = c&3)
    int srow = tid >> 2, sq = (tid & 3) * 8;
    const unsigned short* aP0 = &A[(size_t)(bm + srow) * K + sq];
    const unsigned short* aP1 = aP0 + (size_t)64 * K;
    const unsigned short* bP0 = &BT[(size_t)(bn + srow) * K + sq];
    const unsigned short* bP1 = bP0 + (size_t)64 * K;
    // wave-uniform LDS bases (HW adds lane*16)
    lu32* aL0 = (lu32*)&As[wave * 512];
    lu32* aL1 = (lu32*)&As[2048 + wave * 512];
    lu32* bL0 = (lu32*)&Bs[wave * 512];
    lu32* bL1 = (lu32*)&Bs[2048 + wave * 512];

    f32x4 acc[4][4];
#pragma unroll
    for (int i = 0; i < 4; ++i)
#pragma unroll
        for (int j = 0; j < 4; ++j)
            acc[i][j] = (f32x4){0.f, 0.f, 0.f, 0.f};

    for (int k0 = 0; k0 < K; k0 += 32) {
        __builtin_amdgcn_global_load_lds((gu32*)(aP0 + k0), aL0, 16, 0, 0);
        __builtin_amdgcn_global_load_lds((gu32*)(aP1 + k0), aL1, 16, 0, 0);
        __builtin_amdgcn_global_load_lds((gu32*)(bP0 + k0), bL0, 16, 0, 0);
        __builtin_amdgcn_global_load_lds((gu32*)(bP1 + k0), bL1, 16, 0, 0);
        __syncthreads();
        bf16x8 af[4], bfr[4];
#pragma unroll
        for (int t = 0; t < 4; ++t) {
            af[t]  = *(const bf16x8*)&As[(wm + t * 16 + l16) * 32 + quad * 8];
            bfr[t] = *(const bf16x8*)&Bs[(wn + t * 16 + l16) * 32 + quad * 8];
        }
#pragma unroll
        for (int mt = 0; mt < 4; ++mt)
#pragma unroll
            for (int nt = 0; nt < 4; ++nt)
                acc[mt][nt] = __builtin_amdgcn_mfma_f32_16x16x32_bf16(
                    af[mt], bfr[nt], acc[mt][nt], 0, 0, 0);
        __syncthreads();
    }

    // C/D layout: col = lane&15, row = quad*4 + reg
#pragma unroll
    for (int mt = 0; mt < 4; ++mt)
#pragma unroll
        for (int nt = 0; nt < 4; ++nt) {
            int r0 = bm + wm + mt * 16 + quad * 4;
            int c  = bn + wn + nt * 16 + l16;
            float bv = bias[c];
#pragma unroll
            for (int r = 0; r < 4; ++r) {
                float v = acc[mt][nt][r] + bv;
                if (Cf) Cf[(size_t)(r0 + r) * N + c] = v;
                if (Cb) Cb[(size_t)(r0 + r) * N + c] = f2bf(v);
            }
        }
}

// ---------------------------------------------------------------------------
// Fused bilinear sample + softmax attention.
// One wave per (b,n): 8 heads x 8 lanes, each lane 8 channels (bf16x8 taps).
// refT is bf16 (B, H*W, C). All addressing 32-bit.
// ---------------------------------------------------------------------------
__global__ __launch_bounds__(256) void sample_attn8_k(
    const unsigned short* __restrict__ qb, const float* __restrict__ offb,
    const unsigned short* __restrict__ refT, unsigned short* __restrict__ ob,
    const int* __restrict__ Hp, const int* __restrict__ Wp,
    const int* __restrict__ npp, int B, int N, int C)
{
    int H = *Hp, W = *Wp, npts = *npp;
    int bn = blockIdx.x * 4 + (threadIdx.x >> 6);
    int lane = threadIdx.x & 63;
    int h = lane >> 3;
    int c8 = (lane & 7) << 3;
    int coff = (h << 6) + c8;          // h*HD + c8
    int b = bn / N, n = bn - b * N;
    int row = n / W, col = n - row * W;

    float qv[8];
    unpack8(*(const uint4*)&qb[bn * C + coff], qv);

    const float* op = offb + bn * (NUM_HEADS * MAX_POINTS * 2) + (h << 4);
    const unsigned short* rb = refT + b * N * C;

    float rX = (H > 1) ? (float)(W - 1) / (float)(H - 1) : 0.f;
    float rY = (W > 1) ? (float)(H - 1) / (float)(W - 1) : 0.f;

    float sv[MAX_POINTS][8];
    float lg[MAX_POINTS];
#pragma unroll
    for (int p = 0; p < MAX_POINTS; ++p) {
        float off0 = op[p * 2 + 0];
        float off1 = op[p * 2 + 1];
        float x = ((float)row + off0) * rX;
        float y = ((float)col + off1) * rY;
        float x0f = floorf(x), y0f = floorf(y);
        int x0 = (int)x0f, y0 = (int)y0f;
        float wx1 = x - x0f, wx0 = 1.f - wx1;
        float wy1 = y - y0f, wy0 = 1.f - wy1;

        float a8[8] = {0.f, 0.f, 0.f, 0.f, 0.f, 0.f, 0.f, 0.f};
#pragma unroll
        for (int t = 0; t < 4; ++t) {
            int yi = y0 + (t >> 1);
            int xi = x0 + (t & 1);
            float wgt = ((t >> 1) ? wy1 : wy0) * ((t & 1) ? wx1 : wx0);
            bool ok = ((unsigned)yi < (unsigned)H) & ((unsigned)xi < (unsigned)W);
            float wv = ok ? wgt : 0.f;
            int yc = min(max(yi, 0), H - 1);
            int xc = min(max(xi, 0), W - 1);
            float sf[8];
            unpack8(*(const uint4*)&rb[(yc * W + xc) * C + coff], sf);
#pragma unroll
            for (int j = 0; j < 8; ++j) a8[j] = fmaf(wv, sf[j], a8[j]);
        }
        float t = 0.f;
#pragma unroll
        for (int j = 0; j < 8; ++j) {
            sv[p][j] = a8[j];
            t = fmaf(qv[j], a8[j], t);
        }
        t += __shfl_xor(t, 1);
        t += __shfl_xor(t, 2);
        t += __shfl_xor(t, 4);
        lg[p] = (p < npts) ? t * 0.125f : -1e30f;   // scale = hd^-0.5
    }

    float mx = -1e30f;
#pragma unroll
    for (int p = 0; p < MAX_POINTS; ++p) mx = fmaxf(mx, lg[p]);
    float ssum = 0.f;
#pragma unroll
    for (int p = 0; p < MAX_POINTS; ++p) {
        lg[p] = __expf(lg[p] - mx);
        ssum += lg[p];
    }
    float inv = 1.f / ssum;

    float o8[8] = {0.f, 0.f, 0.f, 0.f, 0.f, 0.f, 0.f, 0.f};
#pragma unroll
    for (int p = 0; p < MAX_POINTS; ++p)
#pragma unroll
        for (int j = 0; j < 8; ++j) o8[j] = fmaf(lg[p], sv[p][j], o8[j]);

    uint4 o;
    o.x = packbf2(o8[0] * inv, o8[1] * inv);
    o.y = packbf2(o8[2] * inv, o8[3] * inv);
    o.z = packbf2(o8[4] * inv, o8[5] * inv);
    o.w = packbf2(o8[6] * inv, o8[7] * inv);
    *(uint4*)&ob[bn * C + coff] = o;
}

// ---------------------------------------------------------------------------
// Launch
// ---------------------------------------------------------------------------
extern "C" void kernel_launch(void* const* d_in, const int* in_sizes, int n_in,
                              void* d_out, int out_size, void* d_ws, size_t ws_size,
                              hipStream_t stream) {
    const float* query = (const float*)d_in[0];
    const float* ref   = (const float*)d_in[1];
    const float* q_w   = (const float*)d_in[2];
    const float* q_b   = (const float*)d_in[3];
    // d_in[4], d_in[5]: kv_w, kv_b -- unused by the reference forward
    const float* off_w = (const float*)d_in[6];
    const float* off_b = (const float*)d_in[7];
    const float* out_w = (const float*)d_in[8];
    const float* out_b = (const float*)d_in[9];
    const int* Hp   = (const int*)d_in[10];
    const int* Wp   = (const int*)d_in[11];
    const int* npp  = (const int*)d_in[12];

    const int C = 512;
    const int B = 4;
    const int H = 64, W = 64;
    const int N = H * W;              // 4096
    const int M = B * N;              // 16384
    const int OFFD = NUM_HEADS * MAX_POINTS * 2;  // 128

    float* offbuf = (float*)d_ws;                                   // M*OFFD f32
    unsigned short* refT_bf = (unsigned short*)(offbuf + (size_t)M * OFFD); // M*C
    unsigned short* qin_bf  = refT_bf + (size_t)M * C;              // M*C
    unsigned short* qbuf_bf = qin_bf  + (size_t)M * C;              // M*C
    unsigned short* obuf_bf = qbuf_bf + (size_t)M * C;              // M*C
    unsigned short* wqT     = obuf_bf + (size_t)M * C;              // C*C
    unsigned short* woffT   = wqT   + (size_t)C * C;                // OFFD*C
    unsigned short* woutT   = woffT + (size_t)OFFD * C;             // C*C

    dim3 blk(256);
    // prep: converts + transposes
    cvt_bf16_k<<<dim3((M * C) / 1024), blk, 0, stream>>>(query, qin_bf, M * C);
    tconv_k<<<dim3(C / 32, C / 32), dim3(32, 8), 0, stream>>>(q_w, wqT, C, C);
    tconv_k<<<dim3(C / 32, OFFD / 32), dim3(32, 8), 0, stream>>>(off_w, woffT, C, OFFD);
    tconv_k<<<dim3(C / 32, C / 32), dim3(32, 8), 0, stream>>>(out_w, woutT, C, C);
    tconv_k<<<dim3(C / 32, N / 32, B), dim3(32, 8), 0, stream>>>(ref, refT_bf, C, N);

    // q projection (bf16 out, 128-tile) and offset projection (fp32 out, 64-tile)
    gemm_bf16_mfma128<<<dim3(C / 128, M / 128), blk, 0, stream>>>(
        qin_bf, wqT, q_b, nullptr, qbuf_bf, M, C, C);
    gemm_bf16_mfma64<<<dim3(OFFD / 64, M / 64), blk, 0, stream>>>(
        qin_bf, woffT, off_b, offbuf, nullptr, M, OFFD, C);

    // fused sample + attention -> bf16 obuf
    sample_attn8_k<<<dim3(M / 4), blk, 0, stream>>>(
        qbuf_bf, offbuf, refT_bf, obuf_bf, Hp, Wp, npp, B, N, C);

    // output projection (fp32 out, 128-tile)
    gemm_bf16_mfma128<<<dim3(C / 128, M / 128), blk, 0, stream>>>(
        obuf_bf, woutT, out_b, (float*)d_out, nullptr, M, C, C);
}

// Round 5
// 220.250 us; speedup vs baseline: 2.8664x; 1.0202x over previous
//
#include <hip/hip_runtime.h>
#include <cmath>

#define NUM_HEADS 8
#define MAX_POINTS 8
#define HD 64
// fixed problem shape (launch config already assumes these)
#define SH 64
#define SW 64
#define SC 512

typedef short bf16x8 __attribute__((ext_vector_type(8)));
typedef float f32x4 __attribute__((ext_vector_type(4)));

typedef const __attribute__((address_space(1))) unsigned int gu32;
typedef __attribute__((address_space(3))) unsigned int lu32;

__device__ __forceinline__ unsigned short f2bf(float f) {
    unsigned u = __float_as_uint(f);
    unsigned r = (u + 0x7fff + ((u >> 16) & 1)) >> 16;   // RNE
    return (unsigned short)r;
}
__device__ __forceinline__ unsigned packbf2(float a, float b) {
    return (unsigned)f2bf(a) | ((unsigned)f2bf(b) << 16);
}
// unpack uint4 (8 bf16) -> 8 floats
__device__ __forceinline__ void unpack8(uint4 u, float* f) {
    f[0] = __uint_as_float(u.x << 16); f[1] = __uint_as_float(u.x & 0xffff0000u);
    f[2] = __uint_as_float(u.y << 16); f[3] = __uint_as_float(u.y & 0xffff0000u);
    f[4] = __uint_as_float(u.z << 16); f[5] = __uint_as_float(u.z & 0xffff0000u);
    f[6] = __uint_as_float(u.w << 16); f[7] = __uint_as_float(u.w & 0xffff0000u);
}

// ---------------------------------------------------------------------------
// fp32 -> bf16 elementwise convert (n divisible by 4)
// ---------------------------------------------------------------------------
__global__ __launch_bounds__(256) void cvt_bf16_k(
    const float* __restrict__ in, unsigned short* __restrict__ out, int n)
{
    int i = (blockIdx.x * 256 + threadIdx.x) * 4;
    if (i >= n) return;
    float4 v = *(const float4*)&in[i];
    ushort4 o;
    o.x = f2bf(v.x); o.y = f2bf(v.y); o.z = f2bf(v.z); o.w = f2bf(v.w);
    *(ushort4*)&out[i] = o;
}

// ---------------------------------------------------------------------------
// Transpose + convert: in (K,N) fp32 -> out (N,K) bf16. 32x32 tiles.
// Batched over blockIdx.z for ref (C,S)->(S,C).
// ---------------------------------------------------------------------------
__global__ __launch_bounds__(256) void tconv_k(
    const float* __restrict__ in, unsigned short* __restrict__ out, int K, int N)
{
    __shared__ float tile[32][33];
    size_t ib = (size_t)blockIdx.z * K * N;
    int k0 = blockIdx.x * 32, n0 = blockIdx.y * 32;
    int tx = threadIdx.x, ty = threadIdx.y;
#pragma unroll
    for (int i = 0; i < 32; i += 8)
        tile[ty + i][tx] = in[ib + (size_t)(k0 + ty + i) * N + n0 + tx];
    __syncthreads();
#pragma unroll
    for (int i = 0; i < 32; i += 8)
        out[ib + (size_t)(n0 + ty + i) * K + k0 + tx] = f2bf(tile[tx][ty + i]);
}

// ---------------------------------------------------------------------------
// Shared MFMA inner loop: 128x128 tile, BK=32, global_load_lds(16B) staging.
// ---------------------------------------------------------------------------
__device__ __forceinline__ void gemm128_core(
    const unsigned short* A, const unsigned short* BT, int K,
    int bm, int bn, int tid, unsigned short* As, unsigned short* Bs,
    f32x4 (&acc)[4][4])
{
    int wave = tid >> 6, lane = tid & 63;
    int quad = lane >> 4, l16 = lane & 15;
    int wm = (wave >> 1) * 64, wn = (wave & 1) * 64;
    int srow = tid >> 2, sq = (tid & 3) * 8;
    const unsigned short* aP0 = &A[(size_t)(bm + srow) * K + sq];
    const unsigned short* aP1 = aP0 + (size_t)64 * K;
    const unsigned short* bP0 = &BT[(size_t)(bn + srow) * K + sq];
    const unsigned short* bP1 = bP0 + (size_t)64 * K;
    lu32* aL0 = (lu32*)&As[wave * 512];
    lu32* aL1 = (lu32*)&As[2048 + wave * 512];
    lu32* bL0 = (lu32*)&Bs[wave * 512];
    lu32* bL1 = (lu32*)&Bs[2048 + wave * 512];

    for (int k0 = 0; k0 < K; k0 += 32) {
        __builtin_amdgcn_global_load_lds((gu32*)(aP0 + k0), aL0, 16, 0, 0);
        __builtin_amdgcn_global_load_lds((gu32*)(aP1 + k0), aL1, 16, 0, 0);
        __builtin_amdgcn_global_load_lds((gu32*)(bP0 + k0), bL0, 16, 0, 0);
        __builtin_amdgcn_global_load_lds((gu32*)(bP1 + k0), bL1, 16, 0, 0);
        __syncthreads();
        bf16x8 af[4], bfr[4];
#pragma unroll
        for (int t = 0; t < 4; ++t) {
            af[t]  = *(const bf16x8*)&As[(wm + t * 16 + l16) * 32 + quad * 8];
            bfr[t] = *(const bf16x8*)&Bs[(wn + t * 16 + l16) * 32 + quad * 8];
        }
#pragma unroll
        for (int mt = 0; mt < 4; ++mt)
#pragma unroll
            for (int nt = 0; nt < 4; ++nt)
                acc[mt][nt] = __builtin_amdgcn_mfma_f32_16x16x32_bf16(
                    af[mt], bfr[nt], acc[mt][nt], 0, 0, 0);
        __syncthreads();
    }
}

// ---------------------------------------------------------------------------
// Fused q+offset projection GEMM: A (M,512) @ BTcat (640,512)^T.
// Cols [0,512) -> qbuf bf16 (stride 512) + q_b; cols [512,640) -> offbuf f32
// (stride 128) + off_b. Branch is block-uniform (bn is per-block).
// ---------------------------------------------------------------------------
__global__ __launch_bounds__(256) void gemm_qoff_k(
    const unsigned short* __restrict__ A, const unsigned short* __restrict__ BT,
    const float* __restrict__ q_b, const float* __restrict__ off_b,
    unsigned short* __restrict__ qout, float* __restrict__ offout,
    int M, int K)
{
    __shared__ unsigned short As[128 * 32];
    __shared__ unsigned short Bs[128 * 32];
    int tid = threadIdx.x;
    int wave = tid >> 6, lane = tid & 63;
    int quad = lane >> 4, l16 = lane & 15;
    int bm = blockIdx.y * 128, bn = blockIdx.x * 128;
    int wm = (wave >> 1) * 64, wn = (wave & 1) * 64;

    f32x4 acc[4][4];
#pragma unroll
    for (int i = 0; i < 4; ++i)
#pragma unroll
        for (int j = 0; j < 4; ++j) acc[i][j] = (f32x4){0.f, 0.f, 0.f, 0.f};

    gemm128_core(A, BT, K, bm, bn, tid, As, Bs, acc);

#pragma unroll
    for (int mt = 0; mt < 4; ++mt)
#pragma unroll
        for (int nt = 0; nt < 4; ++nt) {
            int r0 = bm + wm + mt * 16 + quad * 4;
            int c  = bn + wn + nt * 16 + l16;
            if (bn < 512) {
                float bv = q_b[c];
#pragma unroll
                for (int r = 0; r < 4; ++r)
                    qout[(size_t)(r0 + r) * 512 + c] = f2bf(acc[mt][nt][r] + bv);
            } else {
                int co = c - 512;
                float bv = off_b[co];
#pragma unroll
                for (int r = 0; r < 4; ++r)
                    offout[(size_t)(r0 + r) * 128 + co] = acc[mt][nt][r] + bv;
            }
        }
}

// ---------------------------------------------------------------------------
// Output projection GEMM: fp32 out + bias.
// ---------------------------------------------------------------------------
__global__ __launch_bounds__(256) void gemm_out_k(
    const unsigned short* __restrict__ A, const unsigned short* __restrict__ BT,
    const float* __restrict__ bias, float* __restrict__ Cf, int M, int N, int K)
{
    __shared__ unsigned short As[128 * 32];
    __shared__ unsigned short Bs[128 * 32];
    int tid = threadIdx.x;
    int wave = tid >> 6, lane = tid & 63;
    int quad = lane >> 4, l16 = lane & 15;
    int bm = blockIdx.y * 128, bn = blockIdx.x * 128;
    int wm = (wave >> 1) * 64, wn = (wave & 1) * 64;

    f32x4 acc[4][4];
#pragma unroll
    for (int i = 0; i < 4; ++i)
#pragma unroll
        for (int j = 0; j < 4; ++j) acc[i][j] = (f32x4){0.f, 0.f, 0.f, 0.f};

    gemm128_core(A, BT, K, bm, bn, tid, As, Bs, acc);

#pragma unroll
    for (int mt = 0; mt < 4; ++mt)
#pragma unroll
        for (int nt = 0; nt < 4; ++nt) {
            int r0 = bm + wm + mt * 16 + quad * 4;
            int c  = bn + wn + nt * 16 + l16;
            float bv = bias[c];
#pragma unroll
            for (int r = 0; r < 4; ++r)
                Cf[(size_t)(r0 + r) * N + c] = acc[mt][nt][r] + bv;
        }
}

// ---------------------------------------------------------------------------
// Fused bilinear sample + softmax attention.  One wave per (b,n):
// 8 heads x 8 lanes, each lane 8 channels.  Interior fast path (no clamps);
// fixed 64x64x512 shape -> all addressing is shifts.
// ---------------------------------------------------------------------------
__global__ __launch_bounds__(256) void sample_attn8_k(
    const unsigned short* __restrict__ qb, const float* __restrict__ offb,
    const unsigned short* __restrict__ refT, unsigned short* __restrict__ ob,
    const int* __restrict__ npp)
{
    int npts = *npp;
    int bn = blockIdx.x * 4 + (threadIdx.x >> 6);
    int lane = threadIdx.x & 63;
    int h = lane >> 3;
    int c8 = (lane & 7) << 3;
    int coff = (h << 6) + c8;          // h*HD + c8
    int b = bn >> 12;                  // N = 4096
    int n = bn & 4095;
    int row = n >> 6, col = n & 63;

    float qv[8];
    unpack8(*(const uint4*)&qb[(bn << 9) + coff], qv);

    const float* op = offb + (bn << 7) + (h << 4);
    float4 of4[4];
    of4[0] = *(const float4*)(op + 0);
    of4[1] = *(const float4*)(op + 4);
    of4[2] = *(const float4*)(op + 8);
    of4[3] = *(const float4*)(op + 12);
    const float* offs = (const float*)of4;

    const unsigned short* rb = refT + ((size_t)b << 21);   // b*4096*512

    float sv[MAX_POINTS][8];
    float lg[MAX_POINTS];
#pragma unroll
    for (int p = 0; p < MAX_POINTS; ++p) {
        // H==W -> rX=rY=1
        float x = (float)row + offs[p * 2 + 0];
        float y = (float)col + offs[p * 2 + 1];
        float x0f = floorf(x), y0f = floorf(y);
        int x0 = (int)x0f, y0 = (int)y0f;
        float wx1 = x - x0f, wx0 = 1.f - wx1;
        float wy1 = y - y0f, wy0 = 1.f - wy1;
        float w00 = wy0 * wx0, w01 = wy0 * wx1;
        float w10 = wy1 * wx0, w11 = wy1 * wx1;

        float a8[8];
        if (((unsigned)y0 < 63u) & ((unsigned)x0 < 63u)) {
            // all 4 taps interior: base, +C, +W*C, +W*C+C
            const unsigned short* base = rb + (((y0 << 6) + x0) << 9) + coff;
            float s0[8], s1[8], s2[8], s3[8];
            unpack8(*(const uint4*)(base), s0);
            unpack8(*(const uint4*)(base + 512), s1);
            unpack8(*(const uint4*)(base + 32768), s2);
            unpack8(*(const uint4*)(base + 32768 + 512), s3);
#pragma unroll
            for (int j = 0; j < 8; ++j)
                a8[j] = fmaf(w00, s0[j],
                        fmaf(w01, s1[j],
                        fmaf(w10, s2[j], w11 * s3[j])));
        } else {
#pragma unroll
            for (int j = 0; j < 8; ++j) a8[j] = 0.f;
            float wt[4] = {w00, w01, w10, w11};
#pragma unroll
            for (int t = 0; t < 4; ++t) {
                int yi = y0 + (t >> 1);
                int xi = x0 + (t & 1);
                bool ok = ((unsigned)yi < 64u) & ((unsigned)xi < 64u);
                float wv = ok ? wt[t] : 0.f;
                int yc = min(max(yi, 0), 63);
                int xc = min(max(xi, 0), 63);
                float sf[8];
                unpack8(*(const uint4*)&rb[(((yc << 6) + xc) << 9) + coff], sf);
#pragma unroll
                for (int j = 0; j < 8; ++j) a8[j] = fmaf(wv, sf[j], a8[j]);
            }
        }
        float t = 0.f;
#pragma unroll
        for (int j = 0; j < 8; ++j) {
            sv[p][j] = a8[j];
            t = fmaf(qv[j], a8[j], t);
        }
        t += __shfl_xor(t, 1);
        t += __shfl_xor(t, 2);
        t += __shfl_xor(t, 4);
        lg[p] = (p < npts) ? t * 0.125f : -1e30f;   // scale = hd^-0.5
    }

    float mx = -1e30f;
#pragma unroll
    for (int p = 0; p < MAX_POINTS; ++p) mx = fmaxf(mx, lg[p]);
    float ssum = 0.f;
#pragma unroll
    for (int p = 0; p < MAX_POINTS; ++p) {
        lg[p] = __expf(lg[p] - mx);
        ssum += lg[p];
    }
    float inv = 1.f / ssum;

    float o8[8] = {0.f, 0.f, 0.f, 0.f, 0.f, 0.f, 0.f, 0.f};
#pragma unroll
    for (int p = 0; p < MAX_POINTS; ++p)
#pragma unroll
        for (int j = 0; j < 8; ++j) o8[j] = fmaf(lg[p], sv[p][j], o8[j]);

    uint4 o;
    o.x = packbf2(o8[0] * inv, o8[1] * inv);
    o.y = packbf2(o8[2] * inv, o8[3] * inv);
    o.z = packbf2(o8[4] * inv, o8[5] * inv);
    o.w = packbf2(o8[6] * inv, o8[7] * inv);
    *(uint4*)&ob[(bn << 9) + coff] = o;
}

// ---------------------------------------------------------------------------
// Launch
// ---------------------------------------------------------------------------
extern "C" void kernel_launch(void* const* d_in, const int* in_sizes, int n_in,
                              void* d_out, int out_size, void* d_ws, size_t ws_size,
                              hipStream_t stream) {
    const float* query = (const float*)d_in[0];
    const float* ref   = (const float*)d_in[1];
    const float* q_w   = (const float*)d_in[2];
    const float* q_b   = (const float*)d_in[3];
    // d_in[4], d_in[5]: kv_w, kv_b -- unused by the reference forward
    const float* off_w = (const float*)d_in[6];
    const float* off_b = (const float*)d_in[7];
    const float* out_w = (const float*)d_in[8];
    const float* out_b = (const float*)d_in[9];
    const int* npp  = (const int*)d_in[12];

    const int C = 512;
    const int B = 4;
    const int N = 64 * 64;            // 4096
    const int M = B * N;              // 16384
    const int OFFD = NUM_HEADS * MAX_POINTS * 2;  // 128

    float* offbuf = (float*)d_ws;                                   // M*OFFD f32
    unsigned short* refT_bf = (unsigned short*)(offbuf + (size_t)M * OFFD); // M*C
    unsigned short* qin_bf  = refT_bf + (size_t)M * C;              // M*C
    unsigned short* qbuf_bf = qin_bf  + (size_t)M * C;              // M*C
    unsigned short* obuf_bf = qbuf_bf + (size_t)M * C;              // M*C
    unsigned short* wcat    = obuf_bf + (size_t)M * C;              // (C+OFFD)*C
    unsigned short* woutT   = wcat + (size_t)(C + OFFD) * C;        // C*C

    dim3 blk(256);
    // prep: converts + transposes (wqT rows 0..511 and woffT rows 512..639 of wcat)
    cvt_bf16_k<<<dim3((M * C) / 1024), blk, 0, stream>>>(query, qin_bf, M * C);
    tconv_k<<<dim3(C / 32, C / 32), dim3(32, 8), 0, stream>>>(q_w, wcat, C, C);
    tconv_k<<<dim3(C / 32, OFFD / 32), dim3(32, 8), 0, stream>>>(
        off_w, wcat + (size_t)C * C, C, OFFD);
    tconv_k<<<dim3(C / 32, C / 32), dim3(32, 8), 0, stream>>>(out_w, woutT, C, C);
    tconv_k<<<dim3(C / 32, N / 32, B), dim3(32, 8), 0, stream>>>(ref, refT_bf, C, N);

    // fused q + offset projection (N = 640)
    gemm_qoff_k<<<dim3(5, M / 128), blk, 0, stream>>>(
        qin_bf, wcat, q_b, off_b, qbuf_bf, offbuf, M, C);

    // fused sample + attention -> bf16 obuf
    sample_attn8_k<<<dim3(M / 4), blk, 0, stream>>>(
        qbuf_bf, offbuf, refT_bf, obuf_bf, npp);

    // output projection (fp32 out)
    gemm_out_k<<<dim3(C / 128, M / 128), blk, 0, stream>>>(
        obuf_bf, woutT, out_b, (float*)d_out, M, C, C);
}

// Round 6
// 218.309 us; speedup vs baseline: 2.8919x; 1.0089x over previous
//
#include <hip/hip_runtime.h>
#include <cmath>

#define NUM_HEADS 8
#define MAX_POINTS 8
#define HD 64

typedef short bf16x8 __attribute__((ext_vector_type(8)));
typedef float f32x4 __attribute__((ext_vector_type(4)));

typedef const __attribute__((address_space(1))) unsigned int gu32;
typedef __attribute__((address_space(3))) unsigned int lu32;

__device__ __forceinline__ unsigned short f2bf(float f) {
    unsigned u = __float_as_uint(f);
    unsigned r = (u + 0x7fff + ((u >> 16) & 1)) >> 16;   // RNE
    return (unsigned short)r;
}
__device__ __forceinline__ unsigned packbf2(float a, float b) {
    return (unsigned)f2bf(a) | ((unsigned)f2bf(b) << 16);
}
// unpack uint4 (8 bf16) -> 8 floats
__device__ __forceinline__ void unpack8(uint4 u, float* f) {
    f[0] = __uint_as_float(u.x << 16); f[1] = __uint_as_float(u.x & 0xffff0000u);
    f[2] = __uint_as_float(u.y << 16); f[3] = __uint_as_float(u.y & 0xffff0000u);
    f[4] = __uint_as_float(u.z << 16); f[5] = __uint_as_float(u.z & 0xffff0000u);
    f[6] = __uint_as_float(u.w << 16); f[7] = __uint_as_float(u.w & 0xffff0000u);
}

// ---------------------------------------------------------------------------
// fp32 -> bf16 elementwise convert (n divisible by 4)
// ---------------------------------------------------------------------------
__global__ __launch_bounds__(256) void cvt_bf16_k(
    const float* __restrict__ in, unsigned short* __restrict__ out, int n)
{
    int i = (blockIdx.x * 256 + threadIdx.x) * 4;
    if (i >= n) return;
    float4 v = *(const float4*)&in[i];
    ushort4 o;
    o.x = f2bf(v.x); o.y = f2bf(v.y); o.z = f2bf(v.z); o.w = f2bf(v.w);
    *(ushort4*)&out[i] = o;
}

// ---------------------------------------------------------------------------
// Transpose + convert: in (K,N) fp32 -> out (N,K) bf16. 32x32 tiles.
// Batched over blockIdx.z for ref (C,S)->(S,C).
// ---------------------------------------------------------------------------
__global__ __launch_bounds__(256) void tconv_k(
    const float* __restrict__ in, unsigned short* __restrict__ out, int K, int N)
{
    __shared__ float tile[32][33];
    size_t ib = (size_t)blockIdx.z * K * N;
    int k0 = blockIdx.x * 32, n0 = blockIdx.y * 32;
    int tx = threadIdx.x, ty = threadIdx.y;
#pragma unroll
    for (int i = 0; i < 32; i += 8)
        tile[ty + i][tx] = in[ib + (size_t)(k0 + ty + i) * N + n0 + tx];
    __syncthreads();
#pragma unroll
    for (int i = 0; i < 32; i += 8)
        out[ib + (size_t)(n0 + ty + i) * K + k0 + tx] = f2bf(tile[tx][ty + i]);
}

// ---------------------------------------------------------------------------
// Merged weight transpose+convert: one launch for q_w, off_w, out_w.
// z=0: q_w (512,512)->wcat rows [0,512); z=1: off_w (512,128)->wcat rows
// [512,640); z=2: out_w (512,512)->woutT.  All K=512.
// ---------------------------------------------------------------------------
__global__ __launch_bounds__(256) void tconvW_k(
    const float* __restrict__ q_w, const float* __restrict__ off_w,
    const float* __restrict__ out_w, unsigned short* __restrict__ wcat,
    unsigned short* __restrict__ woutT)
{
    const float* in; unsigned short* out; int N;
    int z = blockIdx.z;
    if (z == 0)      { in = q_w;   out = wcat;             N = 512; }
    else if (z == 1) { in = off_w; out = wcat + 512 * 512; N = 128;
                       if (blockIdx.y >= 4) return; }
    else             { in = out_w; out = woutT;            N = 512; }
    __shared__ float tile[32][33];
    int k0 = blockIdx.x * 32, n0 = blockIdx.y * 32;
    int tx = threadIdx.x, ty = threadIdx.y;
#pragma unroll
    for (int i = 0; i < 32; i += 8)
        tile[ty + i][tx] = in[(size_t)(k0 + ty + i) * N + n0 + tx];
    __syncthreads();
#pragma unroll
    for (int i = 0; i < 32; i += 8)
        out[(size_t)(n0 + ty + i) * 512 + k0 + tx] = f2bf(tile[tx][ty + i]);
}

// ---------------------------------------------------------------------------
// Shared MFMA inner loop: 128x128 tile, BK=32, global_load_lds(16B) staging.
// ---------------------------------------------------------------------------
__device__ __forceinline__ void gemm128_core(
    const unsigned short* A, const unsigned short* BT, int K,
    int bm, int bn, int tid, unsigned short* As, unsigned short* Bs,
    f32x4 (&acc)[4][4])
{
    int wave = tid >> 6, lane = tid & 63;
    int quad = lane >> 4, l16 = lane & 15;
    int wm = (wave >> 1) * 64, wn = (wave & 1) * 64;
    int srow = tid >> 2, sq = (tid & 3) * 8;
    const unsigned short* aP0 = &A[(size_t)(bm + srow) * K + sq];
    const unsigned short* aP1 = aP0 + (size_t)64 * K;
    const unsigned short* bP0 = &BT[(size_t)(bn + srow) * K + sq];
    const unsigned short* bP1 = bP0 + (size_t)64 * K;
    lu32* aL0 = (lu32*)&As[wave * 512];
    lu32* aL1 = (lu32*)&As[2048 + wave * 512];
    lu32* bL0 = (lu32*)&Bs[wave * 512];
    lu32* bL1 = (lu32*)&Bs[2048 + wave * 512];

    for (int k0 = 0; k0 < K; k0 += 32) {
        __builtin_amdgcn_global_load_lds((gu32*)(aP0 + k0), aL0, 16, 0, 0);
        __builtin_amdgcn_global_load_lds((gu32*)(aP1 + k0), aL1, 16, 0, 0);
        __builtin_amdgcn_global_load_lds((gu32*)(bP0 + k0), bL0, 16, 0, 0);
        __builtin_amdgcn_global_load_lds((gu32*)(bP1 + k0), bL1, 16, 0, 0);
        __syncthreads();
        bf16x8 af[4], bfr[4];
#pragma unroll
        for (int t = 0; t < 4; ++t) {
            af[t]  = *(const bf16x8*)&As[(wm + t * 16 + l16) * 32 + quad * 8];
            bfr[t] = *(const bf16x8*)&Bs[(wn + t * 16 + l16) * 32 + quad * 8];
        }
#pragma unroll
        for (int mt = 0; mt < 4; ++mt)
#pragma unroll
            for (int nt = 0; nt < 4; ++nt)
                acc[mt][nt] = __builtin_amdgcn_mfma_f32_16x16x32_bf16(
                    af[mt], bfr[nt], acc[mt][nt], 0, 0, 0);
        __syncthreads();
    }
}

// ---------------------------------------------------------------------------
// Fused q+offset projection GEMM: A (M,512) @ BTcat (640,512)^T.
// Cols [0,512) -> qbuf bf16 + q_b; cols [512,640) -> offbuf f32 + off_b.
// ---------------------------------------------------------------------------
__global__ __launch_bounds__(256) void gemm_qoff_k(
    const unsigned short* __restrict__ A, const unsigned short* __restrict__ BT,
    const float* __restrict__ q_b, const float* __restrict__ off_b,
    unsigned short* __restrict__ qout, float* __restrict__ offout,
    int M, int K)
{
    __shared__ unsigned short As[128 * 32];
    __shared__ unsigned short Bs[128 * 32];
    int tid = threadIdx.x;
    int wave = tid >> 6, lane = tid & 63;
    int quad = lane >> 4, l16 = lane & 15;
    int bm = blockIdx.y * 128, bn = blockIdx.x * 128;
    int wm = (wave >> 1) * 64, wn = (wave & 1) * 64;

    f32x4 acc[4][4];
#pragma unroll
    for (int i = 0; i < 4; ++i)
#pragma unroll
        for (int j = 0; j < 4; ++j) acc[i][j] = (f32x4){0.f, 0.f, 0.f, 0.f};

    gemm128_core(A, BT, K, bm, bn, tid, As, Bs, acc);

#pragma unroll
    for (int mt = 0; mt < 4; ++mt)
#pragma unroll
        for (int nt = 0; nt < 4; ++nt) {
            int r0 = bm + wm + mt * 16 + quad * 4;
            int c  = bn + wn + nt * 16 + l16;
            if (bn < 512) {
                float bv = q_b[c];
#pragma unroll
                for (int r = 0; r < 4; ++r)
                    qout[(size_t)(r0 + r) * 512 + c] = f2bf(acc[mt][nt][r] + bv);
            } else {
                int co = c - 512;
                float bv = off_b[co];
#pragma unroll
                for (int r = 0; r < 4; ++r)
                    offout[(size_t)(r0 + r) * 128 + co] = acc[mt][nt][r] + bv;
            }
        }
}

// ---------------------------------------------------------------------------
// Output projection GEMM: fp32 out + bias.
// ---------------------------------------------------------------------------
__global__ __launch_bounds__(256) void gemm_out_k(
    const unsigned short* __restrict__ A, const unsigned short* __restrict__ BT,
    const float* __restrict__ bias, float* __restrict__ Cf, int M, int N, int K)
{
    __shared__ unsigned short As[128 * 32];
    __shared__ unsigned short Bs[128 * 32];
    int tid = threadIdx.x;
    int wave = tid >> 6, lane = tid & 63;
    int quad = lane >> 4, l16 = lane & 15;
    int bm = blockIdx.y * 128, bn = blockIdx.x * 128;
    int wm = (wave >> 1) * 64, wn = (wave & 1) * 64;

    f32x4 acc[4][4];
#pragma unroll
    for (int i = 0; i < 4; ++i)
#pragma unroll
        for (int j = 0; j < 4; ++j) acc[i][j] = (f32x4){0.f, 0.f, 0.f, 0.f};

    gemm128_core(A, BT, K, bm, bn, tid, As, Bs, acc);

#pragma unroll
    for (int mt = 0; mt < 4; ++mt)
#pragma unroll
        for (int nt = 0; nt < 4; ++nt) {
            int r0 = bm + wm + mt * 16 + quad * 4;
            int c  = bn + wn + nt * 16 + l16;
            float bv = bias[c];
#pragma unroll
            for (int r = 0; r < 4; ++r)
                Cf[(size_t)(r0 + r) * N + c] = acc[mt][nt][r] + bv;
        }
}

// ---------------------------------------------------------------------------
// Fused bilinear sample + softmax attention.  One wave per (b,n):
// 8 heads x 8 lanes, each lane 8 channels.  Branch-free clamped taps
// (R4 structure — schedules better than interior fast path, see R5 PM);
// sv stash packed bf16 (32 VGPRs instead of 64); fixed 64x64x512 shape.
// ---------------------------------------------------------------------------
__global__ __launch_bounds__(256) void sample_attn8_k(
    const unsigned short* __restrict__ qb, const float* __restrict__ offb,
    const unsigned short* __restrict__ refT, unsigned short* __restrict__ ob,
    const int* __restrict__ npp)
{
    int npts = *npp;
    int bn = blockIdx.x * 4 + (threadIdx.x >> 6);
    int lane = threadIdx.x & 63;
    int h = lane >> 3;
    int c8 = (lane & 7) << 3;
    int coff = (h << 6) + c8;          // h*HD + c8
    int b = bn >> 12;                  // N = 4096
    int n = bn & 4095;
    int row = n >> 6, col = n & 63;

    float qv[8];
    unpack8(*(const uint4*)&qb[(bn << 9) + coff], qv);

    const float* op = offb + (bn << 7) + (h << 4);
    const unsigned short* rb = refT + ((size_t)b << 21) + coff;  // coff folded in

    unsigned svp[MAX_POINTS][4];       // bf16-packed sampled values
    float lg[MAX_POINTS];
#pragma unroll
    for (int p = 0; p < MAX_POINTS; ++p) {
        float2 o2 = *(const float2*)(op + p * 2);
        float x = (float)row + o2.x;   // H==W -> rX=rY=1
        float y = (float)col + o2.y;
        float x0f = floorf(x), y0f = floorf(y);
        int x0 = (int)x0f, y0 = (int)y0f;
        float wx1 = x - x0f, wx0 = 1.f - wx1;
        float wy1 = y - y0f, wy0 = 1.f - wy1;
        float wt[4] = {wy0 * wx0, wy0 * wx1, wy1 * wx0, wy1 * wx1};

        float a8[8] = {0.f, 0.f, 0.f, 0.f, 0.f, 0.f, 0.f, 0.f};
#pragma unroll
        for (int t = 0; t < 4; ++t) {
            int yi = y0 + (t >> 1);
            int xi = x0 + (t & 1);
            bool ok = ((unsigned)yi < 64u) & ((unsigned)xi < 64u);
            float wv = ok ? wt[t] : 0.f;
            int yc = min(max(yi, 0), 63);
            int xc = min(max(xi, 0), 63);
            float sf[8];
            unpack8(*(const uint4*)&rb[((yc << 6) + xc) << 9], sf);
#pragma unroll
            for (int j = 0; j < 8; ++j) a8[j] = fmaf(wv, sf[j], a8[j]);
        }
        float t = 0.f;
#pragma unroll
        for (int j = 0; j < 8; ++j) t = fmaf(qv[j], a8[j], t);
        t += __shfl_xor(t, 1);
        t += __shfl_xor(t, 2);
        t += __shfl_xor(t, 4);
        lg[p] = (p < npts) ? t * 0.125f : -1e30f;   // scale = hd^-0.5

        svp[p][0] = packbf2(a8[0], a8[1]);
        svp[p][1] = packbf2(a8[2], a8[3]);
        svp[p][2] = packbf2(a8[4], a8[5]);
        svp[p][3] = packbf2(a8[6], a8[7]);
    }

    float mx = -1e30f;
#pragma unroll
    for (int p = 0; p < MAX_POINTS; ++p) mx = fmaxf(mx, lg[p]);
    float ssum = 0.f;
#pragma unroll
    for (int p = 0; p < MAX_POINTS; ++p) {
        lg[p] = __expf(lg[p] - mx);
        ssum += lg[p];
    }
    float inv = 1.f / ssum;

    float o8[8] = {0.f, 0.f, 0.f, 0.f, 0.f, 0.f, 0.f, 0.f};
#pragma unroll
    for (int p = 0; p < MAX_POINTS; ++p) {
#pragma unroll
        for (int j = 0; j < 4; ++j) {
            o8[2 * j + 0] = fmaf(lg[p], __uint_as_float(svp[p][j] << 16), o8[2 * j + 0]);
            o8[2 * j + 1] = fmaf(lg[p], __uint_as_float(svp[p][j] & 0xffff0000u), o8[2 * j + 1]);
        }
    }

    uint4 o;
    o.x = packbf2(o8[0] * inv, o8[1] * inv);
    o.y = packbf2(o8[2] * inv, o8[3] * inv);
    o.z = packbf2(o8[4] * inv, o8[5] * inv);
    o.w = packbf2(o8[6] * inv, o8[7] * inv);
    *(uint4*)&ob[(bn << 9) + coff] = o;
}

// ---------------------------------------------------------------------------
// Launch
// ---------------------------------------------------------------------------
extern "C" void kernel_launch(void* const* d_in, const int* in_sizes, int n_in,
                              void* d_out, int out_size, void* d_ws, size_t ws_size,
                              hipStream_t stream) {
    const float* query = (const float*)d_in[0];
    const float* ref   = (const float*)d_in[1];
    const float* q_w   = (const float*)d_in[2];
    const float* q_b   = (const float*)d_in[3];
    // d_in[4], d_in[5]: kv_w, kv_b -- unused by the reference forward
    const float* off_w = (const float*)d_in[6];
    const float* off_b = (const float*)d_in[7];
    const float* out_w = (const float*)d_in[8];
    const float* out_b = (const float*)d_in[9];
    const int* npp  = (const int*)d_in[12];

    const int C = 512;
    const int B = 4;
    const int N = 64 * 64;            // 4096
    const int M = B * N;              // 16384
    const int OFFD = NUM_HEADS * MAX_POINTS * 2;  // 128

    float* offbuf = (float*)d_ws;                                   // M*OFFD f32
    unsigned short* refT_bf = (unsigned short*)(offbuf + (size_t)M * OFFD); // M*C
    unsigned short* qin_bf  = refT_bf + (size_t)M * C;              // M*C
    unsigned short* qbuf_bf = qin_bf  + (size_t)M * C;              // M*C
    unsigned short* obuf_bf = qbuf_bf + (size_t)M * C;              // M*C
    unsigned short* wcat    = obuf_bf + (size_t)M * C;              // (C+OFFD)*C
    unsigned short* woutT   = wcat + (size_t)(C + OFFD) * C;        // C*C

    dim3 blk(256);
    // prep: converts + transposes
    cvt_bf16_k<<<dim3((M * C) / 1024), blk, 0, stream>>>(query, qin_bf, M * C);
    tconvW_k<<<dim3(16, 16, 3), dim3(32, 8), 0, stream>>>(
        q_w, off_w, out_w, wcat, woutT);
    tconv_k<<<dim3(C / 32, N / 32, B), dim3(32, 8), 0, stream>>>(ref, refT_bf, C, N);

    // fused q + offset projection (N = 640)
    gemm_qoff_k<<<dim3(5, M / 128), blk, 0, stream>>>(
        qin_bf, wcat, q_b, off_b, qbuf_bf, offbuf, M, C);

    // fused sample + attention -> bf16 obuf
    sample_attn8_k<<<dim3(M / 4), blk, 0, stream>>>(
        qbuf_bf, offbuf, refT_bf, obuf_bf, npp);

    // output projection (fp32 out)
    gemm_out_k<<<dim3(C / 128, M / 128), blk, 0, stream>>>(
        obuf_bf, woutT, out_b, (float*)d_out, M, C, C);
}

// Round 7
// 212.374 us; speedup vs baseline: 2.9727x; 1.0279x over previous
//
#include <hip/hip_runtime.h>
#include <cmath>

#define NUM_HEADS 8
#define MAX_POINTS 8
#define HD 64

typedef short bf16x8 __attribute__((ext_vector_type(8)));
typedef float f32x4 __attribute__((ext_vector_type(4)));

typedef const __attribute__((address_space(1))) unsigned int gu32;
typedef __attribute__((address_space(3))) unsigned int lu32;

__device__ __forceinline__ unsigned short f2bf(float f) {
    unsigned u = __float_as_uint(f);
    unsigned r = (u + 0x7fff + ((u >> 16) & 1)) >> 16;   // RNE
    return (unsigned short)r;
}
__device__ __forceinline__ unsigned packbf2(float a, float b) {
    return (unsigned)f2bf(a) | ((unsigned)f2bf(b) << 16);
}
// unpack uint4 (8 bf16) -> 8 floats
__device__ __forceinline__ void unpack8(uint4 u, float* f) {
    f[0] = __uint_as_float(u.x << 16); f[1] = __uint_as_float(u.x & 0xffff0000u);
    f[2] = __uint_as_float(u.y << 16); f[3] = __uint_as_float(u.y & 0xffff0000u);
    f[4] = __uint_as_float(u.z << 16); f[5] = __uint_as_float(u.z & 0xffff0000u);
    f[6] = __uint_as_float(u.w << 16); f[7] = __uint_as_float(u.w & 0xffff0000u);
}

// ---------------------------------------------------------------------------
// fp32 -> bf16 elementwise convert (n divisible by 4)
// ---------------------------------------------------------------------------
__global__ __launch_bounds__(256) void cvt_bf16_k(
    const float* __restrict__ in, unsigned short* __restrict__ out, int n)
{
    int i = (blockIdx.x * 256 + threadIdx.x) * 4;
    if (i >= n) return;
    float4 v = *(const float4*)&in[i];
    ushort4 o;
    o.x = f2bf(v.x); o.y = f2bf(v.y); o.z = f2bf(v.z); o.w = f2bf(v.w);
    *(ushort4*)&out[i] = o;
}

// ---------------------------------------------------------------------------
// Transpose + convert: in (K,N) fp32 -> out (N,K) bf16. 32x32 tiles.
// Batched over blockIdx.z for ref (C,S)->(S,C).
// ---------------------------------------------------------------------------
__global__ __launch_bounds__(256) void tconv_k(
    const float* __restrict__ in, unsigned short* __restrict__ out, int K, int N)
{
    __shared__ float tile[32][33];
    size_t ib = (size_t)blockIdx.z * K * N;
    int k0 = blockIdx.x * 32, n0 = blockIdx.y * 32;
    int tx = threadIdx.x, ty = threadIdx.y;
#pragma unroll
    for (int i = 0; i < 32; i += 8)
        tile[ty + i][tx] = in[ib + (size_t)(k0 + ty + i) * N + n0 + tx];
    __syncthreads();
#pragma unroll
    for (int i = 0; i < 32; i += 8)
        out[ib + (size_t)(n0 + ty + i) * K + k0 + tx] = f2bf(tile[tx][ty + i]);
}

// ---------------------------------------------------------------------------
// Merged weight transpose+convert: one launch for q_w, off_w, out_w.
// ---------------------------------------------------------------------------
__global__ __launch_bounds__(256) void tconvW_k(
    const float* __restrict__ q_w, const float* __restrict__ off_w,
    const float* __restrict__ out_w, unsigned short* __restrict__ wcat,
    unsigned short* __restrict__ woutT)
{
    const float* in; unsigned short* out; int N;
    int z = blockIdx.z;
    if (z == 0)      { in = q_w;   out = wcat;             N = 512; }
    else if (z == 1) { in = off_w; out = wcat + 512 * 512; N = 128;
                       if (blockIdx.y >= 4) return; }
    else             { in = out_w; out = woutT;            N = 512; }
    __shared__ float tile[32][33];
    int k0 = blockIdx.x * 32, n0 = blockIdx.y * 32;
    int tx = threadIdx.x, ty = threadIdx.y;
#pragma unroll
    for (int i = 0; i < 32; i += 8)
        tile[ty + i][tx] = in[(size_t)(k0 + ty + i) * N + n0 + tx];
    __syncthreads();
#pragma unroll
    for (int i = 0; i < 32; i += 8)
        out[(size_t)(n0 + ty + i) * 512 + k0 + tx] = f2bf(tile[tx][ty + i]);
}

// ---------------------------------------------------------------------------
// Shared MFMA inner loop: 128x128 tile, BK=32, global_load_lds(16B) staging.
// ---------------------------------------------------------------------------
__device__ __forceinline__ void gemm128_core(
    const unsigned short* A, const unsigned short* BT, int K,
    int bm, int bn, int tid, unsigned short* As, unsigned short* Bs,
    f32x4 (&acc)[4][4])
{
    int wave = tid >> 6, lane = tid & 63;
    int quad = lane >> 4, l16 = lane & 15;
    int wm = (wave >> 1) * 64, wn = (wave & 1) * 64;
    int srow = tid >> 2, sq = (tid & 3) * 8;
    const unsigned short* aP0 = &A[(size_t)(bm + srow) * K + sq];
    const unsigned short* aP1 = aP0 + (size_t)64 * K;
    const unsigned short* bP0 = &BT[(size_t)(bn + srow) * K + sq];
    const unsigned short* bP1 = bP0 + (size_t)64 * K;
    lu32* aL0 = (lu32*)&As[wave * 512];
    lu32* aL1 = (lu32*)&As[2048 + wave * 512];
    lu32* bL0 = (lu32*)&Bs[wave * 512];
    lu32* bL1 = (lu32*)&Bs[2048 + wave * 512];

    for (int k0 = 0; k0 < K; k0 += 32) {
        __builtin_amdgcn_global_load_lds((gu32*)(aP0 + k0), aL0, 16, 0, 0);
        __builtin_amdgcn_global_load_lds((gu32*)(aP1 + k0), aL1, 16, 0, 0);
        __builtin_amdgcn_global_load_lds((gu32*)(bP0 + k0), bL0, 16, 0, 0);
        __builtin_amdgcn_global_load_lds((gu32*)(bP1 + k0), bL1, 16, 0, 0);
        __syncthreads();
        bf16x8 af[4], bfr[4];
#pragma unroll
        for (int t = 0; t < 4; ++t) {
            af[t]  = *(const bf16x8*)&As[(wm + t * 16 + l16) * 32 + quad * 8];
            bfr[t] = *(const bf16x8*)&Bs[(wn + t * 16 + l16) * 32 + quad * 8];
        }
#pragma unroll
        for (int mt = 0; mt < 4; ++mt)
#pragma unroll
            for (int nt = 0; nt < 4; ++nt)
                acc[mt][nt] = __builtin_amdgcn_mfma_f32_16x16x32_bf16(
                    af[mt], bfr[nt], acc[mt][nt], 0, 0, 0);
        __syncthreads();
    }
}

// ---------------------------------------------------------------------------
// Fused q+offset projection GEMM: A (M,512) @ BTcat (640,512)^T.
// ---------------------------------------------------------------------------
__global__ __launch_bounds__(256) void gemm_qoff_k(
    const unsigned short* __restrict__ A, const unsigned short* __restrict__ BT,
    const float* __restrict__ q_b, const float* __restrict__ off_b,
    unsigned short* __restrict__ qout, float* __restrict__ offout,
    int M, int K)
{
    __shared__ unsigned short As[128 * 32];
    __shared__ unsigned short Bs[128 * 32];
    int tid = threadIdx.x;
    int wave = tid >> 6, lane = tid & 63;
    int quad = lane >> 4, l16 = lane & 15;
    int bm = blockIdx.y * 128, bn = blockIdx.x * 128;
    int wm = (wave >> 1) * 64, wn = (wave & 1) * 64;

    f32x4 acc[4][4];
#pragma unroll
    for (int i = 0; i < 4; ++i)
#pragma unroll
        for (int j = 0; j < 4; ++j) acc[i][j] = (f32x4){0.f, 0.f, 0.f, 0.f};

    gemm128_core(A, BT, K, bm, bn, tid, As, Bs, acc);

#pragma unroll
    for (int mt = 0; mt < 4; ++mt)
#pragma unroll
        for (int nt = 0; nt < 4; ++nt) {
            int r0 = bm + wm + mt * 16 + quad * 4;
            int c  = bn + wn + nt * 16 + l16;
            if (bn < 512) {
                float bv = q_b[c];
#pragma unroll
                for (int r = 0; r < 4; ++r)
                    qout[(size_t)(r0 + r) * 512 + c] = f2bf(acc[mt][nt][r] + bv);
            } else {
                int co = c - 512;
                float bv = off_b[co];
#pragma unroll
                for (int r = 0; r < 4; ++r)
                    offout[(size_t)(r0 + r) * 128 + co] = acc[mt][nt][r] + bv;
            }
        }
}

// ---------------------------------------------------------------------------
// Output projection GEMM: fp32 out + bias.
// ---------------------------------------------------------------------------
__global__ __launch_bounds__(256) void gemm_out_k(
    const unsigned short* __restrict__ A, const unsigned short* __restrict__ BT,
    const float* __restrict__ bias, float* __restrict__ Cf, int M, int N, int K)
{
    __shared__ unsigned short As[128 * 32];
    __shared__ unsigned short Bs[128 * 32];
    int tid = threadIdx.x;
    int wave = tid >> 6, lane = tid & 63;
    int quad = lane >> 4, l16 = lane & 15;
    int bm = blockIdx.y * 128, bn = blockIdx.x * 128;
    int wm = (wave >> 1) * 64, wn = (wave & 1) * 64;

    f32x4 acc[4][4];
#pragma unroll
    for (int i = 0; i < 4; ++i)
#pragma unroll
        for (int j = 0; j < 4; ++j) acc[i][j] = (f32x4){0.f, 0.f, 0.f, 0.f};

    gemm128_core(A, BT, K, bm, bn, tid, As, Bs, acc);

#pragma unroll
    for (int mt = 0; mt < 4; ++mt)
#pragma unroll
        for (int nt = 0; nt < 4; ++nt) {
            int r0 = bm + wm + mt * 16 + quad * 4;
            int c  = bn + wn + nt * 16 + l16;
            float bv = bias[c];
#pragma unroll
            for (int r = 0; r < 4; ++r)
                Cf[(size_t)(r0 + r) * N + c] = acc[mt][nt][r] + bv;
        }
}

// ---------------------------------------------------------------------------
// Fused bilinear sample + softmax attention, split-point version.
// Block = 2 queries x 2 waves.  Each wave: 4 of the 8 points for one query
// (halves the serial gather chain, doubles waves in flight).  Softmax
// combined across the 2 waves via LDS (logits + partial outputs).
// XCD swizzle: blocks of batch b land on XCDs {2b,2b+1} so each batch's
// 4 MB ref image fits the 2 XCDs' L2.
// ---------------------------------------------------------------------------
__global__ __launch_bounds__(256) void sample_attn_sp_k(
    const unsigned short* __restrict__ qb, const float* __restrict__ offb,
    const unsigned short* __restrict__ refT, unsigned short* __restrict__ ob,
    const int* __restrict__ npp)
{
    __shared__ float slog[2][NUM_HEADS][MAX_POINTS];   // [q][h][p]
    __shared__ float spart[2][8][64];                  // [q][j][lane]
    int npts = *npp;
    int tid = threadIdx.x;
    int qsel = tid >> 7;              // query within block
    int w = (tid >> 6) & 1;           // wave within query (points 4w..4w+3)
    int lane = tid & 63;
    int h = lane >> 3;
    int j = lane & 7;
    int c8 = j << 3;
    int coff = (h << 6) + c8;

    // XCD swizzle: b = (blockIdx&7)>>1
    int bi = blockIdx.x;
    int grp = bi & 7;
    int b = grp >> 1;
    int idx = ((bi >> 3) << 1) | (grp & 1);   // [0,2048)
    int n = (idx << 1) | qsel;                // [0,4096)
    int bn = (b << 12) | n;
    int row = n >> 6, col = n & 63;

    float qv[8];
    unpack8(*(const uint4*)&qb[(bn << 9) + coff], qv);

    // this wave's 4 points' offsets (8 floats)
    const float* op = offb + (bn << 7) + (h << 4) + (w << 3);
    const unsigned short* rb = refT + ((size_t)b << 21) + coff;

    float sv[4][8];
    float lg[4];
#pragma unroll
    for (int p = 0; p < 4; ++p) {
        float2 o2 = *(const float2*)(op + p * 2);
        float x = (float)row + o2.x;   // H==W -> rX=rY=1
        float y = (float)col + o2.y;
        float x0f = floorf(x), y0f = floorf(y);
        int x0 = (int)x0f, y0 = (int)y0f;
        float wx1 = x - x0f, wx0 = 1.f - wx1;
        float wy1 = y - y0f, wy0 = 1.f - wy1;
        float wt[4] = {wy0 * wx0, wy0 * wx1, wy1 * wx0, wy1 * wx1};

        float a8[8] = {0.f, 0.f, 0.f, 0.f, 0.f, 0.f, 0.f, 0.f};
#pragma unroll
        for (int t = 0; t < 4; ++t) {
            int yi = y0 + (t >> 1);
            int xi = x0 + (t & 1);
            bool ok = ((unsigned)yi < 64u) & ((unsigned)xi < 64u);
            float wv = ok ? wt[t] : 0.f;
            int yc = min(max(yi, 0), 63);
            int xc = min(max(xi, 0), 63);
            float sf[8];
            unpack8(*(const uint4*)&rb[((yc << 6) + xc) << 9], sf);
#pragma unroll
            for (int k = 0; k < 8; ++k) a8[k] = fmaf(wv, sf[k], a8[k]);
        }
        float t = 0.f;
#pragma unroll
        for (int k = 0; k < 8; ++k) {
            sv[p][k] = a8[k];
            t = fmaf(qv[k], a8[k], t);
        }
        t += __shfl_xor(t, 1);
        t += __shfl_xor(t, 2);
        t += __shfl_xor(t, 4);
        lg[p] = ((w * 4 + p) < npts) ? t * 0.125f : -1e30f;
    }

    // publish logits (each 8-lane head group writes its 4; lanes 4-7 dup)
    slog[qsel][h][w * 4 + (j & 3)] = lg[j & 3];
    __syncthreads();

    float l8[8];
#pragma unroll
    for (int k = 0; k < 8; ++k) l8[k] = slog[qsel][h][k];
    float mx = -1e30f;
#pragma unroll
    for (int k = 0; k < 8; ++k) mx = fmaxf(mx, l8[k]);
    float ssum = 0.f;
#pragma unroll
    for (int k = 0; k < 8; ++k) {
        l8[k] = __expf(l8[k] - mx);
        ssum += l8[k];
    }
    float inv = 1.f / ssum;

    // partial weighted sum over this wave's 4 points
    float o8[8];
#pragma unroll
    for (int k = 0; k < 8; ++k)
        o8[k] = l8[w * 4 + 0] * sv[0][k] + l8[w * 4 + 1] * sv[1][k]
              + l8[w * 4 + 2] * sv[2][k] + l8[w * 4 + 3] * sv[3][k];

    if (w == 1) {
#pragma unroll
        for (int k = 0; k < 8; ++k) spart[qsel][k][lane] = o8[k];
    }
    __syncthreads();
    if (w == 0) {
#pragma unroll
        for (int k = 0; k < 8; ++k) o8[k] += spart[qsel][k][lane];
        uint4 o;
        o.x = packbf2(o8[0] * inv, o8[1] * inv);
        o.y = packbf2(o8[2] * inv, o8[3] * inv);
        o.z = packbf2(o8[4] * inv, o8[5] * inv);
        o.w = packbf2(o8[6] * inv, o8[7] * inv);
        *(uint4*)&ob[(bn << 9) + coff] = o;
    }
}

// ---------------------------------------------------------------------------
// Launch
// ---------------------------------------------------------------------------
extern "C" void kernel_launch(void* const* d_in, const int* in_sizes, int n_in,
                              void* d_out, int out_size, void* d_ws, size_t ws_size,
                              hipStream_t stream) {
    const float* query = (const float*)d_in[0];
    const float* ref   = (const float*)d_in[1];
    const float* q_w   = (const float*)d_in[2];
    const float* q_b   = (const float*)d_in[3];
    // d_in[4], d_in[5]: kv_w, kv_b -- unused by the reference forward
    const float* off_w = (const float*)d_in[6];
    const float* off_b = (const float*)d_in[7];
    const float* out_w = (const float*)d_in[8];
    const float* out_b = (const float*)d_in[9];
    const int* npp  = (const int*)d_in[12];

    const int C = 512;
    const int B = 4;
    const int N = 64 * 64;            // 4096
    const int M = B * N;              // 16384
    const int OFFD = NUM_HEADS * MAX_POINTS * 2;  // 128

    float* offbuf = (float*)d_ws;                                   // M*OFFD f32
    unsigned short* refT_bf = (unsigned short*)(offbuf + (size_t)M * OFFD); // M*C
    unsigned short* qin_bf  = refT_bf + (size_t)M * C;              // M*C
    unsigned short* qbuf_bf = qin_bf  + (size_t)M * C;              // M*C
    unsigned short* obuf_bf = qbuf_bf + (size_t)M * C;              // M*C
    unsigned short* wcat    = obuf_bf + (size_t)M * C;              // (C+OFFD)*C
    unsigned short* woutT   = wcat + (size_t)(C + OFFD) * C;        // C*C

    dim3 blk(256);
    // prep: converts + transposes
    cvt_bf16_k<<<dim3((M * C) / 1024), blk, 0, stream>>>(query, qin_bf, M * C);
    tconvW_k<<<dim3(16, 16, 3), dim3(32, 8), 0, stream>>>(
        q_w, off_w, out_w, wcat, woutT);
    tconv_k<<<dim3(C / 32, N / 32, B), dim3(32, 8), 0, stream>>>(ref, refT_bf, C, N);

    // fused q + offset projection (N = 640)
    gemm_qoff_k<<<dim3(5, M / 128), blk, 0, stream>>>(
        qin_bf, wcat, q_b, off_b, qbuf_bf, offbuf, M, C);

    // fused sample + attention -> bf16 obuf (2 queries/block, 2 waves/query)
    sample_attn_sp_k<<<dim3(M / 2), blk, 0, stream>>>(
        qbuf_bf, offbuf, refT_bf, obuf_bf, npp);

    // output projection (fp32 out)
    gemm_out_k<<<dim3(C / 128, M / 128), blk, 0, stream>>>(
        obuf_bf, woutT, out_b, (float*)d_out, M, C, C);
}